// Round 14
// baseline (225.108 us; speedup 1.0000x reference)
//
#include <hip/hip_runtime.h>
#include <hip/hip_bf16.h>
#include <math.h>

#define NS 32768   // samples
#define NC 1000    // classes
#define CP 1024    // padded classes
#define DD 1024    // feature dim
#define KN 16      // KNN

typedef __attribute__((ext_vector_type(8))) short bf16x8;
typedef __attribute__((ext_vector_type(4))) float f32x4;
typedef __attribute__((ext_vector_type(4))) float float4v;
typedef __attribute__((ext_vector_type(4))) int int4v;
typedef __attribute__((ext_vector_type(8))) unsigned short u16x8;
typedef __attribute__((ext_vector_type(4))) unsigned short u16x4;

__device__ __forceinline__ unsigned short f2bf(float f) {
  unsigned u = __float_as_uint(f);
  u += 0x7FFFu + ((u >> 16) & 1u);          // RNE
  return (unsigned short)(u >> 16);
}
__device__ __forceinline__ float bf2f(unsigned short h) {
  return __uint_as_float(((unsigned)h) << 16);
}

#define GLL16(g, l) __builtin_amdgcn_global_load_lds( \
    (const __attribute__((address_space(1))) void*)(g), \
    (__attribute__((address_space(3))) void*)(l), 16, 0, 0)

// ---------------- fused prep: score / cast feat / cast cent ---------------
// R13 structure with ONE fix: feat-cast is now lane-coalesced. Old code had
// thread t read float4s 2t,2t+1 (32 B lane stride -> 2x cache-line
// over-request on 60% of the stream). New: flat float4 index
// f = b*1024 + r*256 + tid -> 16 B/lane loads, 8 B/lane stores, both
// perfectly coalesced. Same values, same RNE.
#define PREP_FEAT_BLKS (NS * DD / 4 / 1024)   // 8192 blocks x 1024 float4
__global__ __launch_bounds__(256) void k_prep(
    const float* __restrict__ Cm, unsigned short* __restrict__ Cb,
    float* __restrict__ cnorm2, float* __restrict__ invc,
    const float* __restrict__ A, unsigned short* __restrict__ Ab,
    const float* __restrict__ P, float* __restrict__ scores) {
  __shared__ float red[4];
  __shared__ float wmax[4];
  __shared__ double wsum[4];
  int b = blockIdx.x, tid = threadIdx.x;
  int lane = tid & 63, wid = tid >> 6;
  if (b < NS) {
    // ---- score: max softmax prob of pred row b (block-per-row)
    const float* row = P + (size_t)b * NC;
    bool act = tid < 250;                 // 250*4 = 1000
    float p0 = 0, p1 = 0, p2 = 0, p3 = 0, mx = -1e30f;
    if (act) {
      float4v v = *(const float4v*)(row + tid * 4);   // 16 B/lane, coalesced
      p0 = v[0]; p1 = v[1]; p2 = v[2]; p3 = v[3];
      mx = fmaxf(fmaxf(p0, p1), fmaxf(p2, p3));
    }
    for (int off = 32; off; off >>= 1) mx = fmaxf(mx, __shfl_xor(mx, off));
    if (!lane) wmax[wid] = mx;
    __syncthreads();
    float m = fmaxf(fmaxf(wmax[0], wmax[1]), fmaxf(wmax[2], wmax[3]));
    double s = 0.0;
    if (act)
      s = (double)__expf(p0 - m) + (double)__expf(p1 - m) +
          (double)__expf(p2 - m) + (double)__expf(p3 - m);
    for (int off = 32; off; off >>= 1) s += __shfl_xor(s, off);
    if (!lane) wsum[wid] = s;
    __syncthreads();
    if (!tid) scores[b] = (float)(1.0 / (wsum[0] + wsum[1] + wsum[2] + wsum[3]));
  } else if (b < NS + PREP_FEAT_BLKS) {
    // ---- cast feature -> bf16, coalesced: 4 rounds of consecutive float4
    int bb = b - NS;
    const float4v* src = (const float4v*)A;
    u16x4* dst = (u16x4*)Ab;
#pragma unroll
    for (int r = 0; r < 4; ++r) {
      size_t f = (size_t)bb * 1024 + r * 256 + tid;
      float4v v = src[f];
      u16x4 o = { f2bf(v[0]), f2bf(v[1]), f2bf(v[2]), f2bf(v[3]) };
      dst[f] = o;
    }
  } else {
    // ---- cast centroids -> bf16 (padded to 1024 rows) + norms
    int c = b - NS - PREP_FEAT_BLKS;      // 0..1023
    float sq = 0.f;
    if (c < NC) {
      float4v v = ((const float4v*)(Cm + (size_t)c * DD))[tid];
      sq = v[0]*v[0] + v[1]*v[1] + v[2]*v[2] + v[3]*v[3];
      u16x4 o = { f2bf(v[0]), f2bf(v[1]), f2bf(v[2]), f2bf(v[3]) };
      *(u16x4*)(Cb + (size_t)c * DD + tid * 4) = o;
    } else {
      u16x4 z = { 0, 0, 0, 0 };
      *(u16x4*)(Cb + (size_t)c * DD + tid * 4) = z;
    }
    for (int off = 32; off; off >>= 1) sq += __shfl_xor(sq, off);
    if (!lane) red[wid] = sq;
    __syncthreads();
    if (!tid) {
      float s = red[0] + red[1] + red[2] + red[3];
      cnorm2[c] = s;
      float n = sqrtf(s); if (n < 1e-8f) n = 1e-8f;
      invc[c] = (c < NC) ? 1.0f / n : 0.0f;
    }
  }
}

// ---------------- GEMM: dot[i][c] = sum_k feat[i,k]*cent[c,k]  (bf16) -----
// R7 version (verified 80.8us): 256x256 tile, BK=32, 8 waves, 512 threads,
// 4 LDS buffers, all-global_load_lds staging, ONE raw s_barrier per K-step,
// counted vmcnt(4). T1 XCD swizzle, T2 granule-XOR (conflicts=0), T5 setprio.
#define MF(a_, b_, c_) __builtin_amdgcn_mfma_f32_16x16x32_bf16(a_, b_, c_, 0, 0, 0)
#define RD(base_, i_) (*(const bf16x8*)((base_) + (i_) * 1024 + aoff))
#define SA(s_, b_) do { \
    GLL16(pA0 + (s_) * 32, ldsB + (b_) * 16384 + dA0); \
    GLL16(pA1 + (s_) * 32, ldsB + (b_) * 16384 + dA1); } while (0)
#define SB(s_, b_) do { \
    GLL16(pB0 + (s_) * 32, ldsB + 65536 + (b_) * 16384 + dA0); \
    GLL16(pB1 + (s_) * 32, ldsB + 65536 + (b_) * 16384 + dA1); } while (0)
#define VM4 asm volatile("s_waitcnt vmcnt(4)" ::: "memory")
#define VM0 asm volatile("s_waitcnt vmcnt(0)" ::: "memory")
#define MFMAC(A0_, A1_, A2_, A3_, M0) do { \
    acc[M0+0][0] = MF(A0_, bv0, acc[M0+0][0]); \
    acc[M0+0][1] = MF(A0_, bv1, acc[M0+0][1]); \
    acc[M0+0][2] = MF(A0_, bv2, acc[M0+0][2]); \
    acc[M0+0][3] = MF(A0_, bv3, acc[M0+0][3]); \
    acc[M0+1][0] = MF(A1_, bv0, acc[M0+1][0]); \
    acc[M0+1][1] = MF(A1_, bv1, acc[M0+1][1]); \
    acc[M0+1][2] = MF(A1_, bv2, acc[M0+1][2]); \
    acc[M0+1][3] = MF(A1_, bv3, acc[M0+1][3]); \
    acc[M0+2][0] = MF(A2_, bv0, acc[M0+2][0]); \
    acc[M0+2][1] = MF(A2_, bv1, acc[M0+2][1]); \
    acc[M0+2][2] = MF(A2_, bv2, acc[M0+2][2]); \
    acc[M0+2][3] = MF(A2_, bv3, acc[M0+2][3]); \
    acc[M0+3][0] = MF(A3_, bv0, acc[M0+3][0]); \
    acc[M0+3][1] = MF(A3_, bv1, acc[M0+3][1]); \
    acc[M0+3][2] = MF(A3_, bv2, acc[M0+3][2]); \
    acc[M0+3][3] = MF(A3_, bv3, acc[M0+3][3]); } while (0)
#define KSTEP(s_, STAGE_, GATE_) do { \
    const char* Ab_ = ldsB + ((s_) & 3) * 16384 + wrOff; \
    const char* Bb_ = ldsB + 65536 + ((s_) & 3) * 16384 + wcOff; \
    af0 = RD(Ab_, 0); af1 = RD(Ab_, 1); af2 = RD(Ab_, 2); af3 = RD(Ab_, 3); \
    bv0 = RD(Bb_, 0); bv1 = RD(Bb_, 1); bv2 = RD(Bb_, 2); bv3 = RD(Bb_, 3); \
    af4 = RD(Ab_, 4); af5 = RD(Ab_, 5); af6 = RD(Ab_, 6); af7 = RD(Ab_, 7); \
    STAGE_; \
    __builtin_amdgcn_s_setprio(1); \
    MFMAC(af0, af1, af2, af3, 0); \
    MFMAC(af4, af5, af6, af7, 4); \
    __builtin_amdgcn_s_setprio(0); \
    GATE_; \
    __builtin_amdgcn_s_barrier(); \
  } while (0)

__global__ __launch_bounds__(512, 1) void k_gemm(
    const unsigned short* __restrict__ A,   // [NS][DD] bf16
    const unsigned short* __restrict__ B,   // [CP][DD] bf16
    unsigned short* __restrict__ Dout) {    // [NS][CP] bf16
  __shared__ unsigned short lds[65536];     // 128 KiB: A bufs @0, B bufs @64KB
  char* ldsB = (char*)lds;
  int tid = threadIdx.x, lane = tid & 63, wid = tid >> 6;
  int wr = wid >> 2, wc = wid & 3;
  int bid = (blockIdx.x & 7) * 64 + (blockIdx.x >> 3);   // T1 bijective (512%8==0)
  int cb = bid & 3, rb = bid >> 2;
  int brow = rb * 256, bcol = cb * 256;

  f32x4 acc[8][4];
#pragma unroll
  for (int m = 0; m < 8; ++m)
#pragma unroll
    for (int n = 0; n < 4; ++n) acc[m][n] = (f32x4){0.f, 0.f, 0.f, 0.f};

  // staging: panel = 256 rows x 32 k (16 KB) = 1024 granules of 16B;
  // physical granule (row,pg) holds logical k-granule gl = pg ^ ((row>>1)&3)
  // (inverse-swizzled global source; rule #21 both-sides involution).
  int f0 = wid * 64 + lane, f1 = f0 + 512;
  int gl0 = (f0 & 3) ^ ((f0 >> 3) & 3);
  int gl1 = (f1 & 3) ^ ((f1 >> 3) & 3);
  const unsigned short* pA0 = A + (size_t)(brow + (f0 >> 2)) * DD + gl0 * 8;
  const unsigned short* pA1 = A + (size_t)(brow + (f1 >> 2)) * DD + gl1 * 8;
  const unsigned short* pB0 = B + (size_t)(bcol + (f0 >> 2)) * DD + gl0 * 8;
  const unsigned short* pB1 = B + (size_t)(bcol + (f1 >> 2)) * DD + gl1 * 8;
  int dA0 = f0 * 16, dA1 = f1 * 16;   // linear LDS dest (16B granules)

  // ds_read: row = fragbase + (lane&15), k-granule g = lane>>4,
  // byte = row*64 + (g ^ ((lane>>1)&3))*16.
  int aoff = (lane & 15) * 64 + (((lane >> 4) ^ ((lane >> 1) & 3)) * 16);
  int wrOff = wr * 8192;    // A: 128 rows per wr
  int wcOff = wc * 4096;    // B: 64 rows per wc

  bf16x8 af0, af1, af2, af3, af4, af5, af6, af7, bv0, bv1, bv2, bv3;

  // prologue: stage steps 0,1; land step 0 (leave step 1's 4 in flight).
  SA(0, 0); SB(0, 0);
  SA(1, 1); SB(1, 1);
  VM4;
  __builtin_amdgcn_s_barrier();

  for (int s = 0; s < 30; ++s) {
    int bn = (s + 2) & 3;
    KSTEP(s, { SA(s + 2, bn); SB(s + 2, bn); }, VM4);
  }
  KSTEP(30, (void)0, VM0);        // drain step 31's loads
  KSTEP(31, (void)0, (void)0);

  // epilogue: C/D layout col=lane&15, row=(lane>>4)*4+j
  int colb = bcol + wc * 64 + (lane & 15);
  int rowb = brow + wr * 128 + ((lane >> 4) << 2);
#pragma unroll
  for (int m = 0; m < 8; ++m)
#pragma unroll
    for (int n = 0; n < 4; ++n)
#pragma unroll
      for (int j = 0; j < 4; ++j)
        Dout[(size_t)(rowb + m * 16 + j) * CP + colb + n * 16] = f2bf(acc[m][n][j]);
}

// ---------------- per-row argmax (+ fp64 margin refine) -------------------
__global__ __launch_bounds__(256) void k_argmax(
    const unsigned short* __restrict__ Dot, const float* __restrict__ invc,
    const float* __restrict__ cnorm2, const float* __restrict__ feat,
    const float* __restrict__ cent, float* __restrict__ label_out,
    int* __restrict__ lidx) {
  __shared__ float s_inv[CP], s_cn[CP];
  int tid = threadIdx.x;
#pragma unroll
  for (int q = 0; q < 4; ++q) {
    int c = q * 256 + tid;
    s_inv[c] = invc[c]; s_cn[c] = cnorm2[c];
  }
  __syncthreads();
  int lane = tid & 63, wid = tid >> 6;
  int i = blockIdx.x * 4 + wid;
  const unsigned short* drow = Dot + (size_t)i * CP;

  float v[16];
  float dmax = -1e30f; int darg = CP;
  float emin = 1e30f;  int earg = CP;
#pragma unroll
  for (int it = 0; it < 16; ++it) {
    int c = it * 64 + lane;
    float val, ev;
    if (c < NC) {
      float d = bf2f(drow[c]);
      val = d * s_inv[c];
      ev = s_cn[c] - 2.0f * d;
    } else { val = -1e30f; ev = 1e30f; }
    v[it] = val;
    if (val > dmax) { dmax = val; darg = c; }   // per-lane c ascending -> first idx
    if (ev < emin)  { emin = ev;  earg = c; }
  }
  for (int off = 32; off; off >>= 1) {
    float om = __shfl_xor(dmax, off); int oi = __shfl_xor(darg, off);
    if (om > dmax || (om == dmax && oi < darg)) { dmax = om; darg = oi; }
    float oe = __shfl_xor(emin, off); int oj = __shfl_xor(earg, off);
    if (oe < emin || (oe == emin && oj < earg)) { emin = oe; earg = oj; }
  }
  // margin-certified candidates (val scale; bf16 GEMM + bf16 store err << 0.15)
  const float MARGIN = 0.15f;
  unsigned long long cmask[16]; int ccnt = 0;
#pragma unroll
  for (int it = 0; it < 16; ++it) {
    int c = it * 64 + lane;
    bool cand = (c < NC) && (v[it] >= dmax - MARGIN);
    cmask[it] = __ballot(cand);
    ccnt += __popcll(cmask[it]);
  }
  int finalArg = darg;
  double cosmax_d = -2.0;
  bool need = (ccnt > 1) || (dmax > 10.0f);
  if (need) {
    float xv[16]; double sx = 0.0;
    const float* xr = feat + (size_t)i * DD;
#pragma unroll
    for (int t = 0; t < 16; ++t) {
      float x = xr[t * 64 + lane]; xv[t] = x; sx += (double)x * (double)x;
    }
    for (int off = 32; off; off >>= 1) sx += __shfl_xor(sx, off);
    double nx = sqrt(sx); if (nx < 1e-8) nx = 1e-8;
    double best = -2.0; int besti = CP;
    for (int it = 0; it < 16; ++it) {
      unsigned long long mk = cmask[it];   // wave-uniform
      while (mk) {
        int b = __builtin_ctzll(mk); mk &= mk - 1;
        int c = it * 64 + b;
        const float* cr = cent + (size_t)c * DD;
        double s = 0.0, s2 = 0.0;
#pragma unroll
        for (int t = 0; t < 16; ++t) {
          double cv = (double)cr[t * 64 + lane];
          s += (double)xv[t] * cv; s2 += cv * cv;
        }
        for (int off = 32; off; off >>= 1) {
          s += __shfl_xor(s, off); s2 += __shfl_xor(s2, off);
        }
        double nc = sqrt(s2); if (nc < 1e-8) nc = 1e-8;
        double cs = s / (nx * nc);
        if (cs > best) { best = cs; besti = c; }   // ascending c => first idx
      }
    }
    finalArg = besti; cosmax_d = best;
  }
  if (!lane) {
    lidx[i] = finalArg;
    float lab = -1.0f;
    // non-refined rows: cos <= dmax/16 <= 0.625 < 0.85 (nx >= 16 whp; else need fired)
    if (need && finalArg == earg && cosmax_d > 0.85) lab = (float)finalArg;
    label_out[i] = lab;
  }
}

// ---------------- top-K scatter replay: one class per block (1 wave) ------
__global__ __launch_bounds__(64) void k_scan(
    const int* __restrict__ lidx, const float* __restrict__ scores,
    const int* __restrict__ uidx, const float* __restrict__ ptn_in,
    const int* __restrict__ fidx_in, float* __restrict__ out_ptn,
    float* __restrict__ out_fidx) {
  int c = blockIdx.x;                // class id, 0..NC-1
  int lane = threadIdx.x;
  float row[KN]; int idx[KN];
#pragma unroll
  for (int j = 0; j < KN; ++j) {
    row[j] = ptn_in[c * KN + j];
    idx[j] = fidx_in[c * KN + j];
  }
  for (int base = 0; base < NS; base += 256) {
    int l0 = lidx[base + lane];
    int l1 = lidx[base + 64 + lane];
    int l2 = lidx[base + 128 + lane];
    int l3 = lidx[base + 192 + lane];
#pragma unroll
    for (int q = 0; q < 4; ++q) {
      int lab = (q == 0) ? l0 : (q == 1) ? l1 : (q == 2) ? l2 : l3;
      unsigned long long m = __ballot(lab == c);
      while (m) {                        // wave-uniform mask -> no divergence
        int b = __builtin_ctzll(m); m &= m - 1;
        int i = base + q * 64 + b;       // ascending i order
        float s = scores[i];             // uniform addr -> scalar load
        int ui = uidx[i];
        int mi = 0; float mn = row[0];
#pragma unroll
        for (int t = 1; t < KN; ++t)
          if (row[t] < mn) { mn = row[t]; mi = t; }   // strict < => first idx
        if (s > mn) {                                 // strict > per reference
#pragma unroll
          for (int t = 0; t < KN; ++t)
            if (t == mi) { row[t] = s; idx[t] = ui; } // static idx, stays in regs
        }
      }
    }
  }
  if (!lane) {
#pragma unroll
    for (int j = 0; j < KN; ++j) {
      out_ptn[c * KN + j] = row[j];
      out_fidx[c * KN + j] = (float)idx[j];
    }
  }
}

extern "C" void kernel_launch(void* const* d_in, const int* in_sizes, int n_in,
                              void* d_out, int out_size, void* d_ws, size_t ws_size,
                              hipStream_t stream) {
  const float* feature = (const float*)d_in[0];
  const float* pred    = (const float*)d_in[1];
  const int*   uidx    = (const int*)d_in[2];
  const float* cent    = (const float*)d_in[3];
  const float* ptn_in  = (const float*)d_in[4];
  const int*   fidx_in = (const int*)d_in[5];
  float* out = (float*)d_out;

  char* ws = (char*)d_ws;
  unsigned short* cent_bf = (unsigned short*)(ws);                              // 2 MiB
  unsigned short* feat_bf = (unsigned short*)(ws + (2ull << 20));               // 64 MiB
  unsigned short* dot_bf  = (unsigned short*)(ws + (66ull << 20));              // 64 MiB
  float* scores = (float*)(ws + (130ull << 20));                                // 128 KiB
  int*   lidx   = (int*)  (ws + (130ull << 20) + (128ull << 10));               // 128 KiB
  float* cnorm2 = (float*)(ws + (130ull << 20) + (256ull << 10));               // 4 KiB
  float* invc   = (float*)(ws + (130ull << 20) + (260ull << 10));               // 4 KiB

  hipLaunchKernelGGL(k_prep, dim3(NS + PREP_FEAT_BLKS + CP), dim3(256), 0, stream,
                     cent, cent_bf, cnorm2, invc,
                     feature, feat_bf, pred, scores);
  hipLaunchKernelGGL(k_gemm, dim3((NS / 256) * (CP / 256)), dim3(512), 0, stream,
                     feat_bf, cent_bf, dot_bf);
  hipLaunchKernelGGL(k_argmax, dim3(NS / 4), dim3(256), 0, stream,
                     dot_bf, invc, cnorm2, feature, cent, out, lidx);
  hipLaunchKernelGGL(k_scan, dim3(NC), dim3(64), 0, stream,
                     lidx, scores, uidx, ptn_in, fidx_in,
                     out + NS, out + NS + NC * KN);
}

// Round 15
// 217.193 us; speedup vs baseline: 1.0364x; 1.0364x over previous
//
#include <hip/hip_runtime.h>
#include <hip/hip_bf16.h>
#include <math.h>

#define NS 32768   // samples
#define NC 1000    // classes
#define CP 1024    // padded classes
#define DD 1024    // feature dim
#define KN 16      // KNN

typedef __attribute__((ext_vector_type(8))) short bf16x8;
typedef __attribute__((ext_vector_type(4))) float f32x4;
typedef __attribute__((ext_vector_type(4))) float float4v;
typedef __attribute__((ext_vector_type(4))) int int4v;
typedef __attribute__((ext_vector_type(8))) unsigned short u16x8;
typedef __attribute__((ext_vector_type(4))) unsigned short u16x4;

__device__ __forceinline__ unsigned short f2bf(float f) {
  unsigned u = __float_as_uint(f);
  u += 0x7FFFu + ((u >> 16) & 1u);          // RNE
  return (unsigned short)(u >> 16);
}
__device__ __forceinline__ float bf2f(unsigned short h) {
  return __uint_as_float(((unsigned)h) << 16);
}

#define GLL16(g, l) __builtin_amdgcn_global_load_lds( \
    (const __attribute__((address_space(1))) void*)(g), \
    (__attribute__((address_space(3))) void*)(l), 16, 0, 0)

// ---------------- fused prep: score / cast feat / cast cent ---------------
// R13/R14 structure (best measured prep ~93-96us). Unchanged this round.
#define PREP_FEAT_BLKS (NS * DD / 4 / 1024)   // 8192 blocks x 1024 float4
__global__ __launch_bounds__(256) void k_prep(
    const float* __restrict__ Cm, unsigned short* __restrict__ Cb,
    float* __restrict__ cnorm2, float* __restrict__ invc,
    const float* __restrict__ A, unsigned short* __restrict__ Ab,
    const float* __restrict__ P, float* __restrict__ scores) {
  __shared__ float red[4];
  __shared__ float wmax[4];
  __shared__ double wsum[4];
  int b = blockIdx.x, tid = threadIdx.x;
  int lane = tid & 63, wid = tid >> 6;
  if (b < NS) {
    // ---- score: max softmax prob of pred row b (block-per-row)
    const float* row = P + (size_t)b * NC;
    bool act = tid < 250;                 // 250*4 = 1000
    float p0 = 0, p1 = 0, p2 = 0, p3 = 0, mx = -1e30f;
    if (act) {
      float4v v = *(const float4v*)(row + tid * 4);   // 16 B/lane, coalesced
      p0 = v[0]; p1 = v[1]; p2 = v[2]; p3 = v[3];
      mx = fmaxf(fmaxf(p0, p1), fmaxf(p2, p3));
    }
    for (int off = 32; off; off >>= 1) mx = fmaxf(mx, __shfl_xor(mx, off));
    if (!lane) wmax[wid] = mx;
    __syncthreads();
    float m = fmaxf(fmaxf(wmax[0], wmax[1]), fmaxf(wmax[2], wmax[3]));
    double s = 0.0;
    if (act)
      s = (double)__expf(p0 - m) + (double)__expf(p1 - m) +
          (double)__expf(p2 - m) + (double)__expf(p3 - m);
    for (int off = 32; off; off >>= 1) s += __shfl_xor(s, off);
    if (!lane) wsum[wid] = s;
    __syncthreads();
    if (!tid) scores[b] = (float)(1.0 / (wsum[0] + wsum[1] + wsum[2] + wsum[3]));
  } else if (b < NS + PREP_FEAT_BLKS) {
    // ---- cast feature -> bf16, coalesced: 4 rounds of consecutive float4
    int bb = b - NS;
    const float4v* src = (const float4v*)A;
    u16x4* dst = (u16x4*)Ab;
#pragma unroll
    for (int r = 0; r < 4; ++r) {
      size_t f = (size_t)bb * 1024 + r * 256 + tid;
      float4v v = src[f];
      u16x4 o = { f2bf(v[0]), f2bf(v[1]), f2bf(v[2]), f2bf(v[3]) };
      dst[f] = o;
    }
  } else {
    // ---- cast centroids -> bf16 (padded to 1024 rows) + norms
    int c = b - NS - PREP_FEAT_BLKS;      // 0..1023
    float sq = 0.f;
    if (c < NC) {
      float4v v = ((const float4v*)(Cm + (size_t)c * DD))[tid];
      sq = v[0]*v[0] + v[1]*v[1] + v[2]*v[2] + v[3]*v[3];
      u16x4 o = { f2bf(v[0]), f2bf(v[1]), f2bf(v[2]), f2bf(v[3]) };
      *(u16x4*)(Cb + (size_t)c * DD + tid * 4) = o;
    } else {
      u16x4 z = { 0, 0, 0, 0 };
      *(u16x4*)(Cb + (size_t)c * DD + tid * 4) = z;
    }
    for (int off = 32; off; off >>= 1) sq += __shfl_xor(sq, off);
    if (!lane) red[wid] = sq;
    __syncthreads();
    if (!tid) {
      float s = red[0] + red[1] + red[2] + red[3];
      cnorm2[c] = s;
      float n = sqrtf(s); if (n < 1e-8f) n = 1e-8f;
      invc[c] = (c < NC) ? 1.0f / n : 0.0f;
    }
  }
}

// ---------------- GEMM: dot[i][c] = sum_k feat[i,k]*cent[c,k]  (bf16) -----
// R7 version (verified 80.8us): 256x256 tile, BK=32, 8 waves, 512 threads,
// 4 LDS buffers, all-global_load_lds staging, ONE raw s_barrier per K-step,
// counted vmcnt(4). T1 XCD swizzle, T2 granule-XOR (conflicts=0), T5 setprio.
#define MF(a_, b_, c_) __builtin_amdgcn_mfma_f32_16x16x32_bf16(a_, b_, c_, 0, 0, 0)
#define RD(base_, i_) (*(const bf16x8*)((base_) + (i_) * 1024 + aoff))
#define SA(s_, b_) do { \
    GLL16(pA0 + (s_) * 32, ldsB + (b_) * 16384 + dA0); \
    GLL16(pA1 + (s_) * 32, ldsB + (b_) * 16384 + dA1); } while (0)
#define SB(s_, b_) do { \
    GLL16(pB0 + (s_) * 32, ldsB + 65536 + (b_) * 16384 + dA0); \
    GLL16(pB1 + (s_) * 32, ldsB + 65536 + (b_) * 16384 + dA1); } while (0)
#define VM4 asm volatile("s_waitcnt vmcnt(4)" ::: "memory")
#define VM0 asm volatile("s_waitcnt vmcnt(0)" ::: "memory")
#define MFMAC(A0_, A1_, A2_, A3_, M0) do { \
    acc[M0+0][0] = MF(A0_, bv0, acc[M0+0][0]); \
    acc[M0+0][1] = MF(A0_, bv1, acc[M0+0][1]); \
    acc[M0+0][2] = MF(A0_, bv2, acc[M0+0][2]); \
    acc[M0+0][3] = MF(A0_, bv3, acc[M0+0][3]); \
    acc[M0+1][0] = MF(A1_, bv0, acc[M0+1][0]); \
    acc[M0+1][1] = MF(A1_, bv1, acc[M0+1][1]); \
    acc[M0+1][2] = MF(A1_, bv2, acc[M0+1][2]); \
    acc[M0+1][3] = MF(A1_, bv3, acc[M0+1][3]); \
    acc[M0+2][0] = MF(A2_, bv0, acc[M0+2][0]); \
    acc[M0+2][1] = MF(A2_, bv1, acc[M0+2][1]); \
    acc[M0+2][2] = MF(A2_, bv2, acc[M0+2][2]); \
    acc[M0+2][3] = MF(A2_, bv3, acc[M0+2][3]); \
    acc[M0+3][0] = MF(A3_, bv0, acc[M0+3][0]); \
    acc[M0+3][1] = MF(A3_, bv1, acc[M0+3][1]); \
    acc[M0+3][2] = MF(A3_, bv2, acc[M0+3][2]); \
    acc[M0+3][3] = MF(A3_, bv3, acc[M0+3][3]); } while (0)
#define KSTEP(s_, STAGE_, GATE_) do { \
    const char* Ab_ = ldsB + ((s_) & 3) * 16384 + wrOff; \
    const char* Bb_ = ldsB + 65536 + ((s_) & 3) * 16384 + wcOff; \
    af0 = RD(Ab_, 0); af1 = RD(Ab_, 1); af2 = RD(Ab_, 2); af3 = RD(Ab_, 3); \
    bv0 = RD(Bb_, 0); bv1 = RD(Bb_, 1); bv2 = RD(Bb_, 2); bv3 = RD(Bb_, 3); \
    af4 = RD(Ab_, 4); af5 = RD(Ab_, 5); af6 = RD(Ab_, 6); af7 = RD(Ab_, 7); \
    STAGE_; \
    __builtin_amdgcn_s_setprio(1); \
    MFMAC(af0, af1, af2, af3, 0); \
    MFMAC(af4, af5, af6, af7, 4); \
    __builtin_amdgcn_s_setprio(0); \
    GATE_; \
    __builtin_amdgcn_s_barrier(); \
  } while (0)

__global__ __launch_bounds__(512, 1) void k_gemm(
    const unsigned short* __restrict__ A,   // [NS][DD] bf16
    const unsigned short* __restrict__ B,   // [CP][DD] bf16
    unsigned short* __restrict__ Dout) {    // [NS][CP] bf16
  __shared__ unsigned short lds[65536];     // 128 KiB: A bufs @0, B bufs @64KB
  char* ldsB = (char*)lds;
  int tid = threadIdx.x, lane = tid & 63, wid = tid >> 6;
  int wr = wid >> 2, wc = wid & 3;
  int bid = (blockIdx.x & 7) * 64 + (blockIdx.x >> 3);   // T1 bijective (512%8==0)
  int cb = bid & 3, rb = bid >> 2;
  int brow = rb * 256, bcol = cb * 256;

  f32x4 acc[8][4];
#pragma unroll
  for (int m = 0; m < 8; ++m)
#pragma unroll
    for (int n = 0; n < 4; ++n) acc[m][n] = (f32x4){0.f, 0.f, 0.f, 0.f};

  // staging: panel = 256 rows x 32 k (16 KB) = 1024 granules of 16B;
  // physical granule (row,pg) holds logical k-granule gl = pg ^ ((row>>1)&3)
  // (inverse-swizzled global source; rule #21 both-sides involution).
  int f0 = wid * 64 + lane, f1 = f0 + 512;
  int gl0 = (f0 & 3) ^ ((f0 >> 3) & 3);
  int gl1 = (f1 & 3) ^ ((f1 >> 3) & 3);
  const unsigned short* pA0 = A + (size_t)(brow + (f0 >> 2)) * DD + gl0 * 8;
  const unsigned short* pA1 = A + (size_t)(brow + (f1 >> 2)) * DD + gl1 * 8;
  const unsigned short* pB0 = B + (size_t)(bcol + (f0 >> 2)) * DD + gl0 * 8;
  const unsigned short* pB1 = B + (size_t)(bcol + (f1 >> 2)) * DD + gl1 * 8;
  int dA0 = f0 * 16, dA1 = f1 * 16;   // linear LDS dest (16B granules)

  // ds_read: row = fragbase + (lane&15), k-granule g = lane>>4,
  // byte = row*64 + (g ^ ((lane>>1)&3))*16.
  int aoff = (lane & 15) * 64 + (((lane >> 4) ^ ((lane >> 1) & 3)) * 16);
  int wrOff = wr * 8192;    // A: 128 rows per wr
  int wcOff = wc * 4096;    // B: 64 rows per wc

  bf16x8 af0, af1, af2, af3, af4, af5, af6, af7, bv0, bv1, bv2, bv3;

  // prologue: stage steps 0,1; land step 0 (leave step 1's 4 in flight).
  SA(0, 0); SB(0, 0);
  SA(1, 1); SB(1, 1);
  VM4;
  __builtin_amdgcn_s_barrier();

  for (int s = 0; s < 30; ++s) {
    int bn = (s + 2) & 3;
    KSTEP(s, { SA(s + 2, bn); SB(s + 2, bn); }, VM4);
  }
  KSTEP(30, (void)0, VM0);        // drain step 31's loads
  KSTEP(31, (void)0, (void)0);

  // epilogue: C/D layout col=lane&15, row=(lane>>4)*4+j
  int colb = bcol + wc * 64 + (lane & 15);
  int rowb = brow + wr * 128 + ((lane >> 4) << 2);
#pragma unroll
  for (int m = 0; m < 8; ++m)
#pragma unroll
    for (int n = 0; n < 4; ++n)
#pragma unroll
      for (int j = 0; j < 4; ++j)
        Dout[(size_t)(rowb + m * 16 + j) * CP + colb + n * 16] = f2bf(acc[m][n][j]);
}

// ---------------- per-row argmax (+ fp64 margin refine), vectorized -------
// R14 postmortem: old version read the 64MB dot matrix as scalar u16
// (2 B/lane, 16 load-instrs/row). New mapping: lane covers 8 CONSECUTIVE
// cols, c = it*512 + lane*8 + j -> one bf16x8 (16 B/lane, 1 KB/wave-instr),
// 2 loads/row. inv/cn read from global as float4 pairs (4 KB, L1-resident)
// -> no LDS, no __syncthreads. Per-lane c still strictly ascending (strict
// > keeps first index); cross-lane min-index tie-break unchanged; refine
// adds explicit (cs==best && c<besti) tie-guard. Same fp64 refine math.
__global__ __launch_bounds__(256) void k_argmax(
    const unsigned short* __restrict__ Dot, const float* __restrict__ invc,
    const float* __restrict__ cnorm2, const float* __restrict__ feat,
    const float* __restrict__ cent, float* __restrict__ label_out,
    int* __restrict__ lidx) {
  int tid = threadIdx.x;
  int lane = tid & 63, wid = tid >> 6;
  int i = blockIdx.x * 4 + wid;
  const unsigned short* drow = Dot + (size_t)i * CP;

  float v[2][8];
  float dmax = -1e30f; int darg = CP;
  float emin = 1e30f;  int earg = CP;
#pragma unroll
  for (int it = 0; it < 2; ++it) {
    int c0 = it * 512 + lane * 8;
    bf16x8 d8 = *(const bf16x8*)(drow + c0);                 // 16 B/lane
    float4v i0 = *(const float4v*)(invc + c0);
    float4v i1 = *(const float4v*)(invc + c0 + 4);
    float4v n0 = *(const float4v*)(cnorm2 + c0);
    float4v n1 = *(const float4v*)(cnorm2 + c0 + 4);
#pragma unroll
    for (int j = 0; j < 8; ++j) {
      int c = c0 + j;
      float inv = (j < 4) ? i0[j] : i1[j - 4];
      float cn  = (j < 4) ? n0[j] : n1[j - 4];
      float d = bf2f((unsigned short)d8[j]);
      float val, ev;
      if (c < NC) { val = d * inv; ev = cn - 2.0f * d; }
      else        { val = -1e30f;  ev = 1e30f; }
      v[it][j] = val;
      if (val > dmax) { dmax = val; darg = c; }   // per-lane c ascending
      if (ev < emin)  { emin = ev;  earg = c; }
    }
  }
  for (int off = 32; off; off >>= 1) {
    float om = __shfl_xor(dmax, off); int oi = __shfl_xor(darg, off);
    if (om > dmax || (om == dmax && oi < darg)) { dmax = om; darg = oi; }
    float oe = __shfl_xor(emin, off); int oj = __shfl_xor(earg, off);
    if (oe < emin || (oe == emin && oj < earg)) { emin = oe; earg = oj; }
  }
  // margin-certified candidates (bf16 GEMM + bf16 store err << 0.15)
  const float MARGIN = 0.15f;
  unsigned long long cmask[2][8]; int ccnt = 0;
#pragma unroll
  for (int it = 0; it < 2; ++it)
#pragma unroll
    for (int j = 0; j < 8; ++j) {
      int c = it * 512 + lane * 8 + j;
      bool cand = (c < NC) && (v[it][j] >= dmax - MARGIN);
      cmask[it][j] = __ballot(cand);
      ccnt += __popcll(cmask[it][j]);
    }
  int finalArg = darg;
  double cosmax_d = -2.0;
  bool need = (ccnt > 1) || (dmax > 10.0f);
  if (need) {
    float xv[16]; double sx = 0.0;
    const float* xr = feat + (size_t)i * DD;
#pragma unroll
    for (int t = 0; t < 16; ++t) {
      float x = xr[t * 64 + lane]; xv[t] = x; sx += (double)x * (double)x;
    }
    for (int off = 32; off; off >>= 1) sx += __shfl_xor(sx, off);
    double nx = sqrt(sx); if (nx < 1e-8) nx = 1e-8;
    double best = -2.0; int besti = CP;
#pragma unroll
    for (int it = 0; it < 2; ++it)
#pragma unroll
      for (int j = 0; j < 8; ++j) {
        unsigned long long mk = cmask[it][j];   // wave-uniform
        while (mk) {
          int b = __builtin_ctzll(mk); mk &= mk - 1;
          int c = it * 512 + b * 8 + j;
          const float* cr = cent + (size_t)c * DD;
          double s = 0.0, s2 = 0.0;
#pragma unroll
          for (int t = 0; t < 16; ++t) {
            double cv = (double)cr[t * 64 + lane];
            s += (double)xv[t] * cv; s2 += cv * cv;
          }
          for (int off = 32; off; off >>= 1) {
            s += __shfl_xor(s, off); s2 += __shfl_xor(s2, off);
          }
          double nc = sqrt(s2); if (nc < 1e-8) nc = 1e-8;
          double cs = s / (nx * nc);
          if (cs > best || (cs == best && c < besti)) { best = cs; besti = c; }
        }
      }
    finalArg = besti; cosmax_d = best;
  }
  if (!lane) {
    lidx[i] = finalArg;
    float lab = -1.0f;
    // non-refined rows: cos <= dmax/16 <= 0.625 < 0.85 (nx >= 16 whp; else need fired)
    if (need && finalArg == earg && cosmax_d > 0.85) lab = (float)finalArg;
    label_out[i] = lab;
  }
}

// ---------------- top-K scatter replay: one class per block (1 wave) ------
__global__ __launch_bounds__(64) void k_scan(
    const int* __restrict__ lidx, const float* __restrict__ scores,
    const int* __restrict__ uidx, const float* __restrict__ ptn_in,
    const int* __restrict__ fidx_in, float* __restrict__ out_ptn,
    float* __restrict__ out_fidx) {
  int c = blockIdx.x;                // class id, 0..NC-1
  int lane = threadIdx.x;
  float row[KN]; int idx[KN];
#pragma unroll
  for (int j = 0; j < KN; ++j) {
    row[j] = ptn_in[c * KN + j];
    idx[j] = fidx_in[c * KN + j];
  }
  for (int base = 0; base < NS; base += 256) {
    int l0 = lidx[base + lane];
    int l1 = lidx[base + 64 + lane];
    int l2 = lidx[base + 128 + lane];
    int l3 = lidx[base + 192 + lane];
#pragma unroll
    for (int q = 0; q < 4; ++q) {
      int lab = (q == 0) ? l0 : (q == 1) ? l1 : (q == 2) ? l2 : l3;
      unsigned long long m = __ballot(lab == c);
      while (m) {                        // wave-uniform mask -> no divergence
        int b = __builtin_ctzll(m); m &= m - 1;
        int i = base + q * 64 + b;       // ascending i order
        float s = scores[i];             // uniform addr -> scalar load
        int ui = uidx[i];
        int mi = 0; float mn = row[0];
#pragma unroll
        for (int t = 1; t < KN; ++t)
          if (row[t] < mn) { mn = row[t]; mi = t; }   // strict < => first idx
        if (s > mn) {                                 // strict > per reference
#pragma unroll
          for (int t = 0; t < KN; ++t)
            if (t == mi) { row[t] = s; idx[t] = ui; } // static idx, stays in regs
        }
      }
    }
  }
  if (!lane) {
#pragma unroll
    for (int j = 0; j < KN; ++j) {
      out_ptn[c * KN + j] = row[j];
      out_fidx[c * KN + j] = (float)idx[j];
    }
  }
}

extern "C" void kernel_launch(void* const* d_in, const int* in_sizes, int n_in,
                              void* d_out, int out_size, void* d_ws, size_t ws_size,
                              hipStream_t stream) {
  const float* feature = (const float*)d_in[0];
  const float* pred    = (const float*)d_in[1];
  const int*   uidx    = (const int*)d_in[2];
  const float* cent    = (const float*)d_in[3];
  const float* ptn_in  = (const float*)d_in[4];
  const int*   fidx_in = (const int*)d_in[5];
  float* out = (float*)d_out;

  char* ws = (char*)d_ws;
  unsigned short* cent_bf = (unsigned short*)(ws);                              // 2 MiB
  unsigned short* feat_bf = (unsigned short*)(ws + (2ull << 20));               // 64 MiB
  unsigned short* dot_bf  = (unsigned short*)(ws + (66ull << 20));              // 64 MiB
  float* scores = (float*)(ws + (130ull << 20));                                // 128 KiB
  int*   lidx   = (int*)  (ws + (130ull << 20) + (128ull << 10));               // 128 KiB
  float* cnorm2 = (float*)(ws + (130ull << 20) + (256ull << 10));               // 4 KiB
  float* invc   = (float*)(ws + (130ull << 20) + (260ull << 10));               // 4 KiB

  hipLaunchKernelGGL(k_prep, dim3(NS + PREP_FEAT_BLKS + CP), dim3(256), 0, stream,
                     cent, cent_bf, cnorm2, invc,
                     feature, feat_bf, pred, scores);
  hipLaunchKernelGGL(k_gemm, dim3((NS / 256) * (CP / 256)), dim3(512), 0, stream,
                     feat_bf, cent_bf, dot_bf);
  hipLaunchKernelGGL(k_argmax, dim3(NS / 4), dim3(256), 0, stream,
                     dot_bf, invc, cnorm2, feature, cent, out, lidx);
  hipLaunchKernelGGL(k_scan, dim3(NC), dim3(64), 0, stream,
                     lidx, scores, uidx, ptn_in, fidx_in,
                     out + NS, out + NS + NC * KN);
}